// Round 1
// baseline (264.988 us; speedup 1.0000x reference)
//
#include <hip/hip_runtime.h>
#include <hip/hip_bf16.h>

#define C_DIM 1024
#define H_DIM 512
#define V_DIM 32000
#define B_DIM 16
#define T_DIM 256
#define SPW   8
#define NSLOT 32

typedef unsigned short u16;
typedef unsigned int   u32;
typedef __attribute__((ext_vector_type(8))) short bf16x8;
typedef __attribute__((ext_vector_type(4))) float f32x4;

__device__ __forceinline__ u16 f2b(float f) {
    union { float f; u32 i; } x; x.f = f;
    u32 i = x.i;
    i += 0x7fffu + ((i >> 16) & 1u);   // RNE
    return (u16)(i >> 16);
}
__device__ __forceinline__ float b2f(u16 u) {
    union { u32 i; float f; } x; x.i = ((u32)u) << 16; return x.f;
}
__device__ __forceinline__ float dot8_bf16(uint4 u, const float4 tw0, const float4 tw1) {
    return tw0.x * b2f((u16)(u.x & 0xffff)) + tw0.y * b2f((u16)(u.x >> 16))
         + tw0.z * b2f((u16)(u.y & 0xffff)) + tw0.w * b2f((u16)(u.y >> 16))
         + tw1.x * b2f((u16)(u.z & 0xffff)) + tw1.y * b2f((u16)(u.z >> 16))
         + tw1.z * b2f((u16)(u.w & 0xffff)) + tw1.w * b2f((u16)(u.w >> 16));
}
// 8 consecutive f32 -> 8 bf16 packed as uint4 (RNE, identical to old cvt pass)
__device__ __forceinline__ uint4 cvt8(const float* p) {
    float4 a = *(const float4*)p, b = *(const float4*)(p + 4);
    uint4 r;
    r.x = (u32)f2b(a.x) | ((u32)f2b(a.y) << 16);
    r.y = (u32)f2b(a.z) | ((u32)f2b(a.w) << 16);
    r.z = (u32)f2b(b.x) | ((u32)f2b(b.y) << 16);
    r.w = (u32)f2b(b.z) | ((u32)f2b(b.w) << 16);
    return r;
}

// ---------------- MLP layer 1: out = relu(emb_f32 @ W_f32^T + b), bf16 out -----
// z=0,1,2 : three problems.  z=3 : zero Zpart/Ssum/rowsum.
struct Mlp1Args {
    const float* A[3];
    const float* W[3];
    const float* bias[3];
    u16*         out[3];
    float*       zero;
    int          zn;
};

__global__ __launch_bounds__(256) void mlp1_kern(Mlp1Args args)
{
    if (blockIdx.z == 3) {
        int idx = (blockIdx.y * 16 + blockIdx.x) * 256 + threadIdx.x;  // 128 blocks
        for (int i = idx; i < args.zn; i += 128 * 256) args.zero[i] = 0.0f;
        return;
    }
    const int K = H_DIM;
    int z = blockIdx.z;
    const float* A = args.A[z];
    const float* W = args.W[z];
    const float* bias = args.bias[z];
    u16* out = args.out[z];

    __shared__ __align__(16) u16 As[2][64][40];
    __shared__ __align__(16) u16 Bs[2][64][40];
    int tid = threadIdx.x;
    int m0 = blockIdx.x * 64, n0 = blockIdx.y * 64;
    int wave = tid >> 6, lane = tid & 63;
    int wr = wave >> 1, wc = wave & 1;
    int srow = tid >> 2, scol = (tid & 3) << 3;
    int quad = lane >> 4, l16 = lane & 15;
    f32x4 acc[2][2] = {};

    const float* ap = A + (size_t)(m0 + srow) * K + scol;
    const float* bp = W + (size_t)(n0 + srow) * K + scol;

    *(uint4*)&As[0][srow][scol] = cvt8(ap);
    *(uint4*)&Bs[0][srow][scol] = cvt8(bp);
    __syncthreads();
    int cur = 0;
#pragma unroll 1
    for (int k0 = 0; k0 + 32 < K; k0 += 32) {
        uint4 an = cvt8(ap + k0 + 32);
        uint4 bn = cvt8(bp + k0 + 32);
        bf16x8 af0 = *(const bf16x8*)&As[cur][wr * 32 + l16][quad * 8];
        bf16x8 af1 = *(const bf16x8*)&As[cur][wr * 32 + 16 + l16][quad * 8];
        bf16x8 bf0 = *(const bf16x8*)&Bs[cur][wc * 32 + l16][quad * 8];
        bf16x8 bf1 = *(const bf16x8*)&Bs[cur][wc * 32 + 16 + l16][quad * 8];
        acc[0][0] = __builtin_amdgcn_mfma_f32_16x16x32_bf16(af0, bf0, acc[0][0], 0, 0, 0);
        acc[0][1] = __builtin_amdgcn_mfma_f32_16x16x32_bf16(af0, bf1, acc[0][1], 0, 0, 0);
        acc[1][0] = __builtin_amdgcn_mfma_f32_16x16x32_bf16(af1, bf0, acc[1][0], 0, 0, 0);
        acc[1][1] = __builtin_amdgcn_mfma_f32_16x16x32_bf16(af1, bf1, acc[1][1], 0, 0, 0);
        *(uint4*)&As[cur ^ 1][srow][scol] = an;
        *(uint4*)&Bs[cur ^ 1][srow][scol] = bn;
        __syncthreads();
        cur ^= 1;
    }
    {
        bf16x8 af0 = *(const bf16x8*)&As[cur][wr * 32 + l16][quad * 8];
        bf16x8 af1 = *(const bf16x8*)&As[cur][wr * 32 + 16 + l16][quad * 8];
        bf16x8 bf0 = *(const bf16x8*)&Bs[cur][wc * 32 + l16][quad * 8];
        bf16x8 bf1 = *(const bf16x8*)&Bs[cur][wc * 32 + 16 + l16][quad * 8];
        acc[0][0] = __builtin_amdgcn_mfma_f32_16x16x32_bf16(af0, bf0, acc[0][0], 0, 0, 0);
        acc[0][1] = __builtin_amdgcn_mfma_f32_16x16x32_bf16(af0, bf1, acc[0][1], 0, 0, 0);
        acc[1][0] = __builtin_amdgcn_mfma_f32_16x16x32_bf16(af1, bf0, acc[1][0], 0, 0, 0);
        acc[1][1] = __builtin_amdgcn_mfma_f32_16x16x32_bf16(af1, bf1, acc[1][1], 0, 0, 0);
    }
#pragma unroll
    for (int sm = 0; sm < 2; sm++)
#pragma unroll
        for (int sn = 0; sn < 2; sn++) {
            int n = n0 + wc * 32 + sn * 16 + l16;
            float bv = bias[n];
#pragma unroll
            for (int reg = 0; reg < 4; reg++) {
                int m = m0 + wr * 32 + sm * 16 + quad * 4 + reg;
                out[(size_t)m * H_DIM + n] = f2b(fmaxf(acc[sm][sn][reg] + bv, 0.0f));
            }
        }
}

// ---------------- MLP layer 2: out = relu(H_bf16 @ W_f32^T + b) + emb_f32 ------
struct Mlp2Args {
    const u16*   A[3];
    const float* W[3];
    const float* bias[3];
    const float* resid[3];
    u16*         out[3];
};

__global__ __launch_bounds__(256) void mlp2_kern(Mlp2Args args)
{
    const int K = H_DIM;
    int z = blockIdx.z;
    const u16* A = args.A[z];
    const float* W = args.W[z];
    const float* bias = args.bias[z];
    const float* resid = args.resid[z];
    u16* out = args.out[z];

    __shared__ __align__(16) u16 As[2][64][40];
    __shared__ __align__(16) u16 Bs[2][64][40];
    int tid = threadIdx.x;
    int m0 = blockIdx.x * 64, n0 = blockIdx.y * 64;
    int wave = tid >> 6, lane = tid & 63;
    int wr = wave >> 1, wc = wave & 1;
    int srow = tid >> 2, scol = (tid & 3) << 3;
    int quad = lane >> 4, l16 = lane & 15;
    f32x4 acc[2][2] = {};

    const u16* ap = A + (size_t)(m0 + srow) * K + scol;
    const float* bp = W + (size_t)(n0 + srow) * K + scol;

    *(uint4*)&As[0][srow][scol] = *(const uint4*)ap;
    *(uint4*)&Bs[0][srow][scol] = cvt8(bp);
    __syncthreads();
    int cur = 0;
#pragma unroll 1
    for (int k0 = 0; k0 + 32 < K; k0 += 32) {
        uint4 an = *(const uint4*)(ap + k0 + 32);
        uint4 bn = cvt8(bp + k0 + 32);
        bf16x8 af0 = *(const bf16x8*)&As[cur][wr * 32 + l16][quad * 8];
        bf16x8 af1 = *(const bf16x8*)&As[cur][wr * 32 + 16 + l16][quad * 8];
        bf16x8 bf0 = *(const bf16x8*)&Bs[cur][wc * 32 + l16][quad * 8];
        bf16x8 bf1 = *(const bf16x8*)&Bs[cur][wc * 32 + 16 + l16][quad * 8];
        acc[0][0] = __builtin_amdgcn_mfma_f32_16x16x32_bf16(af0, bf0, acc[0][0], 0, 0, 0);
        acc[0][1] = __builtin_amdgcn_mfma_f32_16x16x32_bf16(af0, bf1, acc[0][1], 0, 0, 0);
        acc[1][0] = __builtin_amdgcn_mfma_f32_16x16x32_bf16(af1, bf0, acc[1][0], 0, 0, 0);
        acc[1][1] = __builtin_amdgcn_mfma_f32_16x16x32_bf16(af1, bf1, acc[1][1], 0, 0, 0);
        *(uint4*)&As[cur ^ 1][srow][scol] = an;
        *(uint4*)&Bs[cur ^ 1][srow][scol] = bn;
        __syncthreads();
        cur ^= 1;
    }
    {
        bf16x8 af0 = *(const bf16x8*)&As[cur][wr * 32 + l16][quad * 8];
        bf16x8 af1 = *(const bf16x8*)&As[cur][wr * 32 + 16 + l16][quad * 8];
        bf16x8 bf0 = *(const bf16x8*)&Bs[cur][wc * 32 + l16][quad * 8];
        bf16x8 bf1 = *(const bf16x8*)&Bs[cur][wc * 32 + 16 + l16][quad * 8];
        acc[0][0] = __builtin_amdgcn_mfma_f32_16x16x32_bf16(af0, bf0, acc[0][0], 0, 0, 0);
        acc[0][1] = __builtin_amdgcn_mfma_f32_16x16x32_bf16(af0, bf1, acc[0][1], 0, 0, 0);
        acc[1][0] = __builtin_amdgcn_mfma_f32_16x16x32_bf16(af1, bf0, acc[1][0], 0, 0, 0);
        acc[1][1] = __builtin_amdgcn_mfma_f32_16x16x32_bf16(af1, bf1, acc[1][1], 0, 0, 0);
    }
#pragma unroll
    for (int sm = 0; sm < 2; sm++)
#pragma unroll
        for (int sn = 0; sn < 2; sn++) {
            int n = n0 + wc * 32 + sn * 16 + l16;
            float bv = bias[n];
#pragma unroll
            for (int reg = 0; reg < 4; reg++) {
                int m = m0 + wr * 32 + sm * 16 + quad * 4 + reg;
                float v = fmaxf(acc[sm][sn][reg] + bv, 0.0f) + resid[(size_t)m * H_DIM + n];
                out[(size_t)m * H_DIM + n] = f2b(v);
            }
        }
}

// ---------------- trans GEMM: TL = Rtrans16 @ proj_f32^T, + rowsum atomics -----
__global__ __launch_bounds__(256) void transgemm_kern(
    const u16* __restrict__ A, const float* __restrict__ B,
    float* __restrict__ TL, float* __restrict__ rowsum)
{
    const int K = H_DIM;
    __shared__ __align__(16) u16 As[2][64][40];
    __shared__ __align__(16) u16 Bs[2][64][40];
    int tid = threadIdx.x;
    int m0 = blockIdx.x * 64, n0 = blockIdx.y * 64;
    int wave = tid >> 6, lane = tid & 63;
    int wr = wave >> 1, wc = wave & 1;
    int srow = tid >> 2, scol = (tid & 3) << 3;
    int quad = lane >> 4, l16 = lane & 15;
    f32x4 acc[2][2] = {};

    const u16* ap = A + (size_t)(m0 + srow) * K + scol;
    const float* bp = B + (size_t)(n0 + srow) * K + scol;

    *(uint4*)&As[0][srow][scol] = *(const uint4*)ap;
    *(uint4*)&Bs[0][srow][scol] = cvt8(bp);
    __syncthreads();
    int cur = 0;
#pragma unroll 1
    for (int k0 = 0; k0 + 32 < K; k0 += 32) {
        uint4 an = *(const uint4*)(ap + k0 + 32);
        uint4 bn = cvt8(bp + k0 + 32);
        bf16x8 af0 = *(const bf16x8*)&As[cur][wr * 32 + l16][quad * 8];
        bf16x8 af1 = *(const bf16x8*)&As[cur][wr * 32 + 16 + l16][quad * 8];
        bf16x8 bf0 = *(const bf16x8*)&Bs[cur][wc * 32 + l16][quad * 8];
        bf16x8 bf1 = *(const bf16x8*)&Bs[cur][wc * 32 + 16 + l16][quad * 8];
        acc[0][0] = __builtin_amdgcn_mfma_f32_16x16x32_bf16(af0, bf0, acc[0][0], 0, 0, 0);
        acc[0][1] = __builtin_amdgcn_mfma_f32_16x16x32_bf16(af0, bf1, acc[0][1], 0, 0, 0);
        acc[1][0] = __builtin_amdgcn_mfma_f32_16x16x32_bf16(af1, bf0, acc[1][0], 0, 0, 0);
        acc[1][1] = __builtin_amdgcn_mfma_f32_16x16x32_bf16(af1, bf1, acc[1][1], 0, 0, 0);
        *(uint4*)&As[cur ^ 1][srow][scol] = an;
        *(uint4*)&Bs[cur ^ 1][srow][scol] = bn;
        __syncthreads();
        cur ^= 1;
    }
    {
        bf16x8 af0 = *(const bf16x8*)&As[cur][wr * 32 + l16][quad * 8];
        bf16x8 af1 = *(const bf16x8*)&As[cur][wr * 32 + 16 + l16][quad * 8];
        bf16x8 bf0 = *(const bf16x8*)&Bs[cur][wc * 32 + l16][quad * 8];
        bf16x8 bf1 = *(const bf16x8*)&Bs[cur][wc * 32 + 16 + l16][quad * 8];
        acc[0][0] = __builtin_amdgcn_mfma_f32_16x16x32_bf16(af0, bf0, acc[0][0], 0, 0, 0);
        acc[0][1] = __builtin_amdgcn_mfma_f32_16x16x32_bf16(af0, bf1, acc[0][1], 0, 0, 0);
        acc[1][0] = __builtin_amdgcn_mfma_f32_16x16x32_bf16(af1, bf0, acc[1][0], 0, 0, 0);
        acc[1][1] = __builtin_amdgcn_mfma_f32_16x16x32_bf16(af1, bf1, acc[1][1], 0, 0, 0);
    }
#pragma unroll
    for (int sm = 0; sm < 2; sm++)
#pragma unroll
        for (int reg = 0; reg < 4; reg++) {
            int m = m0 + wr * 32 + sm * 16 + quad * 4 + reg;
            float e = 0.0f;
#pragma unroll
            for (int sn = 0; sn < 2; sn++) {
                int n = n0 + wc * 32 + sn * 16 + l16;
                float v = acc[sm][sn][reg];
                TL[(size_t)m * C_DIM + n] = v;
                e += expf(v);
            }
            e += __shfl_xor(e, 1, 64);
            e += __shfl_xor(e, 2, 64);
            e += __shfl_xor(e, 4, 64);
            e += __shfl_xor(e, 8, 64);
            if (l16 == 0) atomicAdd(rowsum + m, e);
        }
}

// ---------------- fused: emission denominator (zsum) + start logits ------------
__global__ __launch_bounds__(256) void zsum_start_kern(
    const u16* __restrict__ Rterm16, const float* __restrict__ tow,
    const float* __restrict__ tob, const int* __restrict__ w2s,
    float* __restrict__ Zpart,
    const u16* __restrict__ Rstart16, const float* __restrict__ sow,
    const float* __restrict__ sob, float* __restrict__ startv,
    float* __restrict__ Ssum)
{
    int wid = threadIdx.x >> 6, lane = threadIdx.x & 63;
    if (blockIdx.x >= V_DIM / 4) {
        // start-logit path
        int bid = blockIdx.x - V_DIM / 4;
        int c = bid * 4 + wid;
        uint4 rv = ((const uint4*)(Rstart16 + (size_t)c * H_DIM))[lane];
        const float4* wp = (const float4*)(sow);
        float4 w0 = wp[lane * 2], w1 = wp[lane * 2 + 1];
        float d = dot8_bf16(rv, w0, w1);
        for (int off = 1; off < 64; off <<= 1) d += __shfl_xor(d, off, 64);
        if (lane == 0) {
            d += sob[0];
            startv[c] = d;
            atomicAdd(Ssum + (bid & (NSLOT - 1)), expf(d));
        }
        return;
    }
    int v = blockIdx.x * 4 + wid;
    float* slot = Zpart + (blockIdx.x & (NSLOT - 1)) * C_DIM;
    const float4* twp = (const float4*)(tow + (size_t)v * H_DIM);
    float4 tw0 = twp[lane * 2], tw1 = twp[lane * 2 + 1];
    float ob = tob[v];
    int cs[SPW];
#pragma unroll
    for (int s = 0; s < SPW; s++) cs[s] = w2s[v * SPW + s];
    uint4 rv[SPW];
#pragma unroll
    for (int s = 0; s < SPW; s++)
        rv[s] = ((const uint4*)(Rterm16 + (size_t)cs[s] * H_DIM))[lane];
    float d[SPW];
#pragma unroll
    for (int s = 0; s < SPW; s++) {
        d[s] = dot8_bf16(rv[s], tw0, tw1);
        d[s] += __shfl_xor(d[s], 1, 64);
        d[s] += __shfl_xor(d[s], 2, 64);
        d[s] += __shfl_xor(d[s], 4, 64);
    }
    float x = d[0];
    int myc = cs[0];
#pragma unroll
    for (int s = 1; s < SPW; s++) {
        if ((lane & 7) == s) { x = d[s]; myc = cs[s]; }
    }
    x += __shfl_xor(x, 8, 64);
    x += __shfl_xor(x, 16, 64);
    x += __shfl_xor(x, 32, 64);
    u32 dupmask = 0;
#pragma unroll
    for (int s = 1; s < SPW; s++) {
        bool dp = false;
#pragma unroll
        for (int s2 = 0; s2 < s; s2++) dp = dp || (cs[s2] == cs[s]);
        if (dp) dupmask |= (1u << s);
    }
    if (lane < 8 && !((dupmask >> lane) & 1u))
        atomicAdd(slot + myc, expf(x + ob));
}

// ---------------- obs[b,t,s] = term_logit - logZ (zred folded in) ---------------
__global__ __launch_bounds__(256) void obs_kern(
    const u16* __restrict__ Rterm16, const float* __restrict__ tow,
    const float* __restrict__ tob, const int* __restrict__ w2s,
    const int* __restrict__ text, const float* __restrict__ Zpart,
    float* __restrict__ obs)
{
    int wid = threadIdx.x >> 6, lane = threadIdx.x & 63;
    int idx = blockIdx.x * 4 + wid;          // 0 .. B*T-1
    int v = text[idx];
    const float4* twp = (const float4*)(tow + (size_t)v * H_DIM);
    float4 tw0 = twp[lane * 2], tw1 = twp[lane * 2 + 1];
    float ob = tob[v];
    int cs[SPW];
#pragma unroll
    for (int s = 0; s < SPW; s++) cs[s] = w2s[v * SPW + s];
    uint4 rv[SPW];
#pragma unroll
    for (int s = 0; s < SPW; s++)
        rv[s] = ((const uint4*)(Rterm16 + (size_t)cs[s] * H_DIM))[lane];
    float d[SPW];
#pragma unroll
    for (int s = 0; s < SPW; s++) {
        d[s] = dot8_bf16(rv[s], tw0, tw1);
        d[s] += __shfl_xor(d[s], 1, 64);
        d[s] += __shfl_xor(d[s], 2, 64);
        d[s] += __shfl_xor(d[s], 4, 64);
    }
    float x = d[0];
    int myc = cs[0];
#pragma unroll
    for (int s = 1; s < SPW; s++) {
        if ((lane & 7) == s) { x = d[s]; myc = cs[s]; }
    }
    x += __shfl_xor(x, 8, 64);
    x += __shfl_xor(x, 16, 64);
    x += __shfl_xor(x, 32, 64);
    int g = lane >> 3;
    float zp = 0.0f;
#pragma unroll
    for (int k = 0; k < 4; k++)
        zp += Zpart[(size_t)(g * 4 + k) * C_DIM + myc];
    zp += __shfl_xor(zp, 8, 64);
    zp += __shfl_xor(zp, 16, 64);
    zp += __shfl_xor(zp, 32, 64);
    if (lane < 8)
        obs[idx * SPW + lane] = x + ob - logf(zp);
}

// ---------------- log-semiring 8x8 matrix combine (lane = j*8+i) ----------------
__device__ __forceinline__ float lsm_combine(float accv, float mv, int i, int j)
{
    float x[8];
#pragma unroll
    for (int k = 0; k < 8; k++) {
        float a = __shfl(accv, k * 8 + i, 64);   // acc[i][k]
        float b = __shfl(mv,  j * 8 + k, 64);    // m[k][j]
        x[k] = a + b;
    }
    float mx = fmaxf(fmaxf(fmaxf(x[0], x[1]), fmaxf(x[2], x[3])),
                     fmaxf(fmaxf(x[4], x[5]), fmaxf(x[6], x[7])));
    float s = 0.0f;
#pragma unroll
    for (int k = 0; k < 8; k++) s += expf(x[k] - mx);
    return mx + logf(s);
}

// ---------------- fused potential + scan phase A --------------------------------
__global__ __launch_bounds__(256) void scanA_kern(
    const float* __restrict__ TL, const float* __restrict__ rowsum,
    const float* __restrict__ obs, const float* __restrict__ startv,
    const float* __restrict__ Ssum, const int* __restrict__ text,
    const int* __restrict__ w2s, float* __restrict__ Mc)
{
    int wid = threadIdx.x >> 6, lane = threadIdx.x & 63;
    int g = blockIdx.x * 4 + wid;        // 0 .. 255
    int b = g >> 4, c = g & 15;
    int t0 = c * 16;
    int cnt = min(16, (T_DIM - 1) - t0);
    int i = lane & 7, j = lane >> 3;

    const int* txt = text + b * T_DIM;
    const float* obsb = obs + (size_t)b * T_DIM * SPW;

    float logS = 0.0f;
    if (t0 == 0) {
        float ss = 0.0f;
#pragma unroll
        for (int k = 0; k < NSLOT; k++) ss += Ssum[k];
        logS = logf(ss);
    }

    auto potval = [&](int t) -> float {
        int vt  = txt[t];
        int vt1 = txt[t + 1];
        int ci = w2s[vt * SPW + i];
        int cj = w2s[vt1 * SPW + j];
        float p = TL[(size_t)ci * C_DIM + cj] - logf(rowsum[ci]) + obsb[(t + 1) * SPW + j];
        if (t == 0) p += startv[ci] - logS + obsb[i];
        return p;
    };

    float acc = potval(t0);
    if (cnt > 1) {
        float nv = potval(t0 + 1);
        for (int t = t0 + 1; t < t0 + cnt; t++) {
            float nv2 = (t + 1 < t0 + cnt) ? potval(t + 1) : 0.0f;
            acc = lsm_combine(acc, nv, i, j);
            nv = nv2;
        }
    }
    Mc[(size_t)g * 64 + lane] = acc;
}

// ---------------- scan phase B: 16 waves (one per batch), writes d_out ----------
__global__ __launch_bounds__(1024) void scanB_kern(const float* __restrict__ Mc,
                                                   float* __restrict__ out)
{
    int wave = threadIdx.x >> 6, lane = threadIdx.x & 63;
    int i = lane & 7, j = lane >> 3;
    const float* base = Mc + (size_t)wave * 16 * 64;
    float acc = base[lane];
    for (int c = 1; c < 16; c++)
        acc = lsm_combine(acc, base[(size_t)c * 64 + lane], i, j);
    float mx = acc;
    for (int o = 1; o < 64; o <<= 1) mx = fmaxf(mx, __shfl_xor(mx, o, 64));
    float e = expf(acc - mx);
    for (int o = 1; o < 64; o <<= 1) e += __shfl_xor(e, o, 64);
    __shared__ float part[16];
    if (lane == 0) part[wave] = mx + logf(e);
    __syncthreads();
    if (threadIdx.x == 0) {
        float s = 0.0f;
#pragma unroll
        for (int k = 0; k < 16; k++) s += part[k];
        out[0] = s;
    }
}

extern "C" void kernel_launch(void* const* d_in, const int* in_sizes, int n_in,
                              void* d_out, int out_size, void* d_ws, size_t ws_size,
                              hipStream_t stream)
{
    const float* start_emb = (const float*)d_in[0];
    const float* start_l1w = (const float*)d_in[1];
    const float* start_l1b = (const float*)d_in[2];
    const float* start_l2w = (const float*)d_in[3];
    const float* start_l2b = (const float*)d_in[4];
    const float* start_ow  = (const float*)d_in[5];
    const float* start_ob  = (const float*)d_in[6];
    const float* state_emb = (const float*)d_in[7];
    const float* trans_l1w = (const float*)d_in[8];
    const float* trans_l1b = (const float*)d_in[9];
    const float* trans_l2w = (const float*)d_in[10];
    const float* trans_l2b = (const float*)d_in[11];
    const float* proj_w    = (const float*)d_in[12];
    const float* pret_emb  = (const float*)d_in[13];
    const float* term_l1w  = (const float*)d_in[14];
    const float* term_l1b  = (const float*)d_in[15];
    const float* term_l2w  = (const float*)d_in[16];
    const float* term_l2b  = (const float*)d_in[17];
    const float* term_ow   = (const float*)d_in[18];
    const float* term_ob   = (const float*)d_in[19];
    const int*   text      = (const int*)d_in[20];
    const int*   w2s       = (const int*)d_in[21];

    char* w = (char*)d_ws;
    const u32 MB = 1u << 20;
    const size_t CH = (size_t)C_DIM * H_DIM;   // 524288

    u16*   H16    = (u16*)(w);                          // 3 MB: hidden x3
    u16*   R16    = (u16*)(w + 3u * MB);                // 3 MB: Rstart/Rtrans/Rterm
    float* TL     = (float*)(w + 6u * MB);              // 4 MB
    float* startv = (float*)(w + 10u * MB);             // 4 KB
    float* obs    = (float*)(w + 10u * MB + 4096);      // 128 KB
    float* Mc     = (float*)(w + 10u * MB + 4096 + 131072); // 64 KB
    float* Zpart  = (float*)(w + 11u * MB);             // 128 KB
    float* Ssum   = Zpart + (size_t)NSLOT * C_DIM;      // 32 floats
    float* rowsum = Ssum + NSLOT;                       // 1024 floats

    u16* Hs = H16, *Ht = H16 + CH, *Hp = H16 + 2 * CH;
    u16* Rstart16 = R16;
    u16* Rtrans16 = R16 + CH;
    u16* Rterm16  = R16 + 2 * CH;

    dim3 blk256(256);

    Mlp1Args a1;
    a1.A[0] = start_emb; a1.A[1] = state_emb; a1.A[2] = pret_emb;
    a1.W[0] = start_l1w; a1.W[1] = trans_l1w; a1.W[2] = term_l1w;
    a1.bias[0] = start_l1b; a1.bias[1] = trans_l1b; a1.bias[2] = term_l1b;
    a1.out[0] = Hs; a1.out[1] = Ht; a1.out[2] = Hp;
    a1.zero = Zpart;
    a1.zn = NSLOT * C_DIM + NSLOT + C_DIM;

    Mlp2Args a2;
    a2.A[0] = Hs; a2.A[1] = Ht; a2.A[2] = Hp;
    a2.W[0] = start_l2w; a2.W[1] = trans_l2w; a2.W[2] = term_l2w;
    a2.bias[0] = start_l2b; a2.bias[1] = trans_l2b; a2.bias[2] = term_l2b;
    a2.resid[0] = start_emb; a2.resid[1] = state_emb; a2.resid[2] = pret_emb;
    a2.out[0] = Rstart16; a2.out[1] = Rtrans16; a2.out[2] = Rterm16;

    mlp1_kern<<<dim3(16, 8, 4), blk256, 0, stream>>>(a1);
    mlp2_kern<<<dim3(16, 8, 3), blk256, 0, stream>>>(a2);

    transgemm_kern<<<dim3(16, 16), blk256, 0, stream>>>(Rtrans16, proj_w, TL, rowsum);

    zsum_start_kern<<<V_DIM / 4 + C_DIM / 4, blk256, 0, stream>>>(
        Rterm16, term_ow, term_ob, w2s, Zpart,
        Rstart16, start_ow, start_ob, startv, Ssum);

    obs_kern<<<B_DIM * T_DIM / 4, blk256, 0, stream>>>(Rterm16, term_ow, term_ob, w2s,
                                                       text, Zpart, obs);
    scanA_kern<<<B_DIM * 16 / 4, blk256, 0, stream>>>(TL, rowsum, obs, startv, Ssum,
                                                      text, w2s, Mc);
    scanB_kern<<<1, 1024, 0, stream>>>(Mc, (float*)d_out);
}

// Round 2
// 225.979 us; speedup vs baseline: 1.1726x; 1.1726x over previous
//
#include <hip/hip_runtime.h>
#include <hip/hip_bf16.h>

#define C_DIM 1024
#define H_DIM 512
#define V_DIM 32000
#define B_DIM 16
#define T_DIM 256
#define SPW   8
#define NSLOT 32

typedef unsigned short u16;
typedef unsigned int   u32;
typedef __attribute__((ext_vector_type(8))) short bf16x8;
typedef __attribute__((ext_vector_type(4))) float f32x4;

__device__ __forceinline__ u16 f2b(float f) {
    union { float f; u32 i; } x; x.f = f;
    u32 i = x.i;
    i += 0x7fffu + ((i >> 16) & 1u);   // RNE
    return (u16)(i >> 16);
}
__device__ __forceinline__ float b2f(u16 u) {
    union { u32 i; float f; } x; x.i = ((u32)u) << 16; return x.f;
}
__device__ __forceinline__ float dot8_bf16(uint4 u, const float4 tw0, const float4 tw1) {
    return tw0.x * b2f((u16)(u.x & 0xffff)) + tw0.y * b2f((u16)(u.x >> 16))
         + tw0.z * b2f((u16)(u.y & 0xffff)) + tw0.w * b2f((u16)(u.y >> 16))
         + tw1.x * b2f((u16)(u.z & 0xffff)) + tw1.y * b2f((u16)(u.z >> 16))
         + tw1.z * b2f((u16)(u.w & 0xffff)) + tw1.w * b2f((u16)(u.w >> 16));
}

// ---------------- f32 -> bf16 convert (10 segments) + zero segment --------------
struct CvtArgs {
    const float* src[10];
    u16*         dst[10];
    int          n[10];      // element counts (multiples of 4)
    float*       zero;       // Zpart .. Ssum .. rowsum contiguous
    int          zn;
};

__global__ __launch_bounds__(256) void cvt_kern(CvtArgs a)
{
    int seg = blockIdx.y;
    if (seg == 10) {
        for (int i = blockIdx.x * 256 + threadIdx.x; i < a.zn; i += gridDim.x * 256)
            a.zero[i] = 0.0f;
        return;
    }
    const float4* s = (const float4*)a.src[seg];
    ushort4* d = (ushort4*)a.dst[seg];
    int n4 = a.n[seg] >> 2;
    for (int i = blockIdx.x * 256 + threadIdx.x; i < n4; i += gridDim.x * 256) {
        float4 v = s[i];
        ushort4 o;
        o.x = f2b(v.x); o.y = f2b(v.y); o.z = f2b(v.z); o.w = f2b(v.w);
        d[i] = o;
    }
}

// ---------------- batched bf16 MFMA MLP layer (3 problems via z) ----------------
// out16 = relu(A@W^T + bias) (+resid_f32).  M=1024, N=512, K=512. Double-buffered.
struct MlpArgs {
    const u16*   A[3];
    const u16*   W[3];
    const float* bias[3];
    const float* resid[3];   // f32, may be null
    u16*         out[3];
};

__global__ __launch_bounds__(256) void mlp16_kern(MlpArgs args)
{
    const int N = H_DIM, K = H_DIM;
    int z = blockIdx.z;
    const u16* A = args.A[z];
    const u16* B = args.W[z];
    const float* bias = args.bias[z];
    const float* resid = args.resid[z];
    u16* out = args.out[z];

    __shared__ __align__(16) u16 As[2][64][40];
    __shared__ __align__(16) u16 Bs[2][64][40];
    int tid  = threadIdx.x;
    int m0 = blockIdx.x * 64, n0 = blockIdx.y * 64;
    int wave = tid >> 6, lane = tid & 63;
    int wr = wave >> 1, wc = wave & 1;
    int srow = tid >> 2, scol = (tid & 3) << 3;
    int quad = lane >> 4, l16 = lane & 15;
    f32x4 acc[2][2] = {};

    const u16* ap = A + (size_t)(m0 + srow) * K + scol;
    const u16* bp = B + (size_t)(n0 + srow) * K + scol;

    *(uint4*)&As[0][srow][scol] = *(const uint4*)ap;
    *(uint4*)&Bs[0][srow][scol] = *(const uint4*)bp;
    __syncthreads();
    int cur = 0;
#pragma unroll 1
    for (int k0 = 0; k0 + 32 < K; k0 += 32) {
        uint4 an = *(const uint4*)(ap + k0 + 32);
        uint4 bn = *(const uint4*)(bp + k0 + 32);
        bf16x8 af0 = *(const bf16x8*)&As[cur][wr * 32 + l16][quad * 8];
        bf16x8 af1 = *(const bf16x8*)&As[cur][wr * 32 + 16 + l16][quad * 8];
        bf16x8 bf0 = *(const bf16x8*)&Bs[cur][wc * 32 + l16][quad * 8];
        bf16x8 bf1 = *(const bf16x8*)&Bs[cur][wc * 32 + 16 + l16][quad * 8];
        acc[0][0] = __builtin_amdgcn_mfma_f32_16x16x32_bf16(af0, bf0, acc[0][0], 0, 0, 0);
        acc[0][1] = __builtin_amdgcn_mfma_f32_16x16x32_bf16(af0, bf1, acc[0][1], 0, 0, 0);
        acc[1][0] = __builtin_amdgcn_mfma_f32_16x16x32_bf16(af1, bf0, acc[1][0], 0, 0, 0);
        acc[1][1] = __builtin_amdgcn_mfma_f32_16x16x32_bf16(af1, bf1, acc[1][1], 0, 0, 0);
        *(uint4*)&As[cur ^ 1][srow][scol] = an;
        *(uint4*)&Bs[cur ^ 1][srow][scol] = bn;
        __syncthreads();
        cur ^= 1;
    }
    {
        bf16x8 af0 = *(const bf16x8*)&As[cur][wr * 32 + l16][quad * 8];
        bf16x8 af1 = *(const bf16x8*)&As[cur][wr * 32 + 16 + l16][quad * 8];
        bf16x8 bf0 = *(const bf16x8*)&Bs[cur][wc * 32 + l16][quad * 8];
        bf16x8 bf1 = *(const bf16x8*)&Bs[cur][wc * 32 + 16 + l16][quad * 8];
        acc[0][0] = __builtin_amdgcn_mfma_f32_16x16x32_bf16(af0, bf0, acc[0][0], 0, 0, 0);
        acc[0][1] = __builtin_amdgcn_mfma_f32_16x16x32_bf16(af0, bf1, acc[0][1], 0, 0, 0);
        acc[1][0] = __builtin_amdgcn_mfma_f32_16x16x32_bf16(af1, bf0, acc[1][0], 0, 0, 0);
        acc[1][1] = __builtin_amdgcn_mfma_f32_16x16x32_bf16(af1, bf1, acc[1][1], 0, 0, 0);
    }
#pragma unroll
    for (int sm = 0; sm < 2; sm++)
#pragma unroll
        for (int sn = 0; sn < 2; sn++) {
            int n = n0 + wc * 32 + sn * 16 + l16;
            float bv = bias[n];
#pragma unroll
            for (int reg = 0; reg < 4; reg++) {
                int m = m0 + wr * 32 + sm * 16 + quad * 4 + reg;
                float v = fmaxf(acc[sm][sn][reg] + bv, 0.0f);
                if (resid) v += resid[(size_t)m * N + n];
                out[(size_t)m * N + n] = f2b(v);
            }
        }
}

// ---------------- fused: transGEMM(256) + zsum(8000) + startlog(256) ------------
// All three are independent; one launch overlaps compute-bound GEMM with the
// BW-bound term_ow stream.
__global__ __launch_bounds__(256) void fused_mid_kern(
    const u16* __restrict__ Rtrans16, const u16* __restrict__ proj16,
    float* __restrict__ TL, float* __restrict__ rowsum,
    const u16* __restrict__ Rterm16, const float* __restrict__ tow,
    const float* __restrict__ tob, const int* __restrict__ w2s,
    float* __restrict__ Zpart, float* __restrict__ Lmat,
    const u16* __restrict__ Rstart16, const float* __restrict__ sow,
    const float* __restrict__ sob, float* __restrict__ startv,
    float* __restrict__ Ssum)
{
    __shared__ __align__(16) u16 As[2][64][40];
    __shared__ __align__(16) u16 Bs[2][64][40];
    int bx = blockIdx.x;
    int tid = threadIdx.x;
    int wid = tid >> 6, lane = tid & 63;

    if (bx < 256) {
        // ---- trans GEMM: TL = Rtrans16 @ proj16^T, rowsum += sum exp ----
        const int K = H_DIM;
        int m0 = (bx & 15) * 64, n0 = (bx >> 4) * 64;
        int wave = wid;
        int wr = wave >> 1, wc = wave & 1;
        int srow = tid >> 2, scol = (tid & 3) << 3;
        int quad = lane >> 4, l16 = lane & 15;
        f32x4 acc[2][2] = {};

        const u16* ap = Rtrans16 + (size_t)(m0 + srow) * K + scol;
        const u16* bp = proj16 + (size_t)(n0 + srow) * K + scol;

        *(uint4*)&As[0][srow][scol] = *(const uint4*)ap;
        *(uint4*)&Bs[0][srow][scol] = *(const uint4*)bp;
        __syncthreads();
        int cur = 0;
#pragma unroll 1
        for (int k0 = 0; k0 + 32 < K; k0 += 32) {
            uint4 an = *(const uint4*)(ap + k0 + 32);
            uint4 bn = *(const uint4*)(bp + k0 + 32);
            bf16x8 af0 = *(const bf16x8*)&As[cur][wr * 32 + l16][quad * 8];
            bf16x8 af1 = *(const bf16x8*)&As[cur][wr * 32 + 16 + l16][quad * 8];
            bf16x8 bf0 = *(const bf16x8*)&Bs[cur][wc * 32 + l16][quad * 8];
            bf16x8 bf1 = *(const bf16x8*)&Bs[cur][wc * 32 + 16 + l16][quad * 8];
            acc[0][0] = __builtin_amdgcn_mfma_f32_16x16x32_bf16(af0, bf0, acc[0][0], 0, 0, 0);
            acc[0][1] = __builtin_amdgcn_mfma_f32_16x16x32_bf16(af0, bf1, acc[0][1], 0, 0, 0);
            acc[1][0] = __builtin_amdgcn_mfma_f32_16x16x32_bf16(af1, bf0, acc[1][0], 0, 0, 0);
            acc[1][1] = __builtin_amdgcn_mfma_f32_16x16x32_bf16(af1, bf1, acc[1][1], 0, 0, 0);
            *(uint4*)&As[cur ^ 1][srow][scol] = an;
            *(uint4*)&Bs[cur ^ 1][srow][scol] = bn;
            __syncthreads();
            cur ^= 1;
        }
        {
            bf16x8 af0 = *(const bf16x8*)&As[cur][wr * 32 + l16][quad * 8];
            bf16x8 af1 = *(const bf16x8*)&As[cur][wr * 32 + 16 + l16][quad * 8];
            bf16x8 bf0 = *(const bf16x8*)&Bs[cur][wc * 32 + l16][quad * 8];
            bf16x8 bf1 = *(const bf16x8*)&Bs[cur][wc * 32 + 16 + l16][quad * 8];
            acc[0][0] = __builtin_amdgcn_mfma_f32_16x16x32_bf16(af0, bf0, acc[0][0], 0, 0, 0);
            acc[0][1] = __builtin_amdgcn_mfma_f32_16x16x32_bf16(af0, bf1, acc[0][1], 0, 0, 0);
            acc[1][0] = __builtin_amdgcn_mfma_f32_16x16x32_bf16(af1, bf0, acc[1][0], 0, 0, 0);
            acc[1][1] = __builtin_amdgcn_mfma_f32_16x16x32_bf16(af1, bf1, acc[1][1], 0, 0, 0);
        }
#pragma unroll
        for (int sm = 0; sm < 2; sm++)
#pragma unroll
            for (int reg = 0; reg < 4; reg++) {
                int m = m0 + wr * 32 + sm * 16 + quad * 4 + reg;
                float e = 0.0f;
#pragma unroll
                for (int sn = 0; sn < 2; sn++) {
                    int n = n0 + wc * 32 + sn * 16 + l16;
                    float v = acc[sm][sn][reg];
                    TL[(size_t)m * C_DIM + n] = v;
                    e += expf(v);
                }
                e += __shfl_xor(e, 1, 64);
                e += __shfl_xor(e, 2, 64);
                e += __shfl_xor(e, 4, 64);
                e += __shfl_xor(e, 8, 64);
                if (l16 == 0) atomicAdd(rowsum + m, e);
            }
        return;
    }

    if (bx < 256 + V_DIM / 4) {
        // ---- emission logits + denominator ----
        int vbid = bx - 256;
        int v = vbid * 4 + wid;
        float* slot = Zpart + (vbid & (NSLOT - 1)) * C_DIM;
        const float4* twp = (const float4*)(tow + (size_t)v * H_DIM);
        float4 tw0 = twp[lane * 2], tw1 = twp[lane * 2 + 1];
        float ob = tob[v];
        int cs[SPW];
#pragma unroll
        for (int s = 0; s < SPW; s++) cs[s] = w2s[v * SPW + s];
        uint4 rv[SPW];
#pragma unroll
        for (int s = 0; s < SPW; s++)
            rv[s] = ((const uint4*)(Rterm16 + (size_t)cs[s] * H_DIM))[lane];
        float d[SPW];
#pragma unroll
        for (int s = 0; s < SPW; s++) {
            d[s] = dot8_bf16(rv[s], tw0, tw1);
            d[s] += __shfl_xor(d[s], 1, 64);
            d[s] += __shfl_xor(d[s], 2, 64);
            d[s] += __shfl_xor(d[s], 4, 64);
        }
        float x = d[0];
        int myc = cs[0];
#pragma unroll
        for (int s = 1; s < SPW; s++) {
            if ((lane & 7) == s) { x = d[s]; myc = cs[s]; }
        }
        x += __shfl_xor(x, 8, 64);
        x += __shfl_xor(x, 16, 64);
        x += __shfl_xor(x, 32, 64);
        u32 dupmask = 0;
#pragma unroll
        for (int s = 1; s < SPW; s++) {
            bool dp = false;
#pragma unroll
            for (int s2 = 0; s2 < s; s2++) dp = dp || (cs[s2] == cs[s]);
            if (dp) dupmask |= (1u << s);
        }
        if (lane < 8) {
            Lmat[(size_t)v * SPW + lane] = x + ob;
            if (!((dupmask >> lane) & 1u))
                atomicAdd(slot + myc, expf(x + ob));
        }
        return;
    }

    // ---- start logits ----
    int sbid = bx - (256 + V_DIM / 4);
    int c = sbid * 4 + wid;
    uint4 rv = ((const uint4*)(Rstart16 + (size_t)c * H_DIM))[lane];
    const float4* wp = (const float4*)(sow);
    float4 w0 = wp[lane * 2], w1 = wp[lane * 2 + 1];
    float d = dot8_bf16(rv, w0, w1);
    for (int off = 1; off < 64; off <<= 1) d += __shfl_xor(d, off, 64);
    if (lane == 0) {
        d += sob[0];
        startv[c] = d;
        atomicAdd(Ssum + (sbid & (NSLOT - 1)), expf(d));
    }
}

// ---------------- zred: logZ[c], logrow[c] --------------------------------------
__global__ __launch_bounds__(256) void zred_kern(
    const float* __restrict__ Zpart, const float* __restrict__ rowsum,
    float* __restrict__ logZ, float* __restrict__ logrow)
{
    int c = blockIdx.x * 256 + threadIdx.x;   // 1024 total
    float z = 0.0f;
#pragma unroll
    for (int k = 0; k < NSLOT; k++) z += Zpart[(size_t)k * C_DIM + c];
    logZ[c] = logf(z);
    logrow[c] = logf(rowsum[c]);
}

// ---------------- log-semiring 8x8 matrix combine (lane = j*8+i) ----------------
__device__ __forceinline__ float lsm_combine(float accv, float mv, int i, int j)
{
    float x[8];
#pragma unroll
    for (int k = 0; k < 8; k++) {
        float a = __shfl(accv, k * 8 + i, 64);   // acc[i][k]
        float b = __shfl(mv,  j * 8 + k, 64);    // m[k][j]
        x[k] = a + b;
    }
    float mx = fmaxf(fmaxf(fmaxf(x[0], x[1]), fmaxf(x[2], x[3])),
                     fmaxf(fmaxf(x[4], x[5]), fmaxf(x[6], x[7])));
    float s = 0.0f;
#pragma unroll
    for (int k = 0; k < 8; k++) s += expf(x[k] - mx);
    return mx + logf(s);
}

// ---------------- fused potential + scan phase A (1 wave / block) ---------------
__global__ __launch_bounds__(64) void scanA_kern(
    const float* __restrict__ TL, const float* __restrict__ logrow,
    const float* __restrict__ Lmat, const float* __restrict__ logZ,
    const float* __restrict__ startv, const float* __restrict__ Ssum,
    const int* __restrict__ text, const int* __restrict__ w2s,
    float* __restrict__ Mc)
{
    int lane = threadIdx.x;
    int g = blockIdx.x;                  // 0 .. 255
    int b = g >> 4, c = g & 15;
    int t0 = c * 16;
    int cnt = min(16, (T_DIM - 1) - t0);
    int i = lane & 7, j = lane >> 3;

    const int* txt = text + b * T_DIM;

    float logS = 0.0f;
    if (t0 == 0) {
        float ss = 0.0f;
#pragma unroll
        for (int k = 0; k < NSLOT; k++) ss += Ssum[k];
        logS = logf(ss);
    }

    auto potval = [&](int t) -> float {
        int vt  = txt[t];
        int vt1 = txt[t + 1];
        int ci = w2s[vt * SPW + i];
        int cj = w2s[vt1 * SPW + j];
        float p = TL[(size_t)ci * C_DIM + cj] - logrow[ci]
                + Lmat[(size_t)vt1 * SPW + j] - logZ[cj];
        if (t == 0)
            p += startv[ci] - logS + Lmat[(size_t)vt * SPW + i] - logZ[ci];
        return p;
    };

    float acc = potval(t0);
    if (cnt > 1) {
        float nv = potval(t0 + 1);
        for (int t = t0 + 1; t < t0 + cnt; t++) {
            float nv2 = (t + 1 < t0 + cnt) ? potval(t + 1) : 0.0f;
            acc = lsm_combine(acc, nv, i, j);
            nv = nv2;
        }
    }
    Mc[(size_t)g * 64 + lane] = acc;
}

// ---------------- scan phase B: 16 waves (one per batch), writes d_out ----------
__global__ __launch_bounds__(1024) void scanB_kern(const float* __restrict__ Mc,
                                                   float* __restrict__ out)
{
    int wave = threadIdx.x >> 6, lane = threadIdx.x & 63;
    int i = lane & 7, j = lane >> 3;
    const float* base = Mc + (size_t)wave * 16 * 64;
    float acc = base[lane];
    for (int c = 1; c < 16; c++)
        acc = lsm_combine(acc, base[(size_t)c * 64 + lane], i, j);
    float mx = acc;
    for (int o = 1; o < 64; o <<= 1) mx = fmaxf(mx, __shfl_xor(mx, o, 64));
    float e = expf(acc - mx);
    for (int o = 1; o < 64; o <<= 1) e += __shfl_xor(e, o, 64);
    __shared__ float part[16];
    if (lane == 0) part[wave] = mx + logf(e);
    __syncthreads();
    if (threadIdx.x == 0) {
        float s = 0.0f;
#pragma unroll
        for (int k = 0; k < 16; k++) s += part[k];
        out[0] = s;
    }
}

extern "C" void kernel_launch(void* const* d_in, const int* in_sizes, int n_in,
                              void* d_out, int out_size, void* d_ws, size_t ws_size,
                              hipStream_t stream)
{
    const float* start_emb = (const float*)d_in[0];
    const float* start_l1w = (const float*)d_in[1];
    const float* start_l1b = (const float*)d_in[2];
    const float* start_l2w = (const float*)d_in[3];
    const float* start_l2b = (const float*)d_in[4];
    const float* start_ow  = (const float*)d_in[5];
    const float* start_ob  = (const float*)d_in[6];
    const float* state_emb = (const float*)d_in[7];
    const float* trans_l1w = (const float*)d_in[8];
    const float* trans_l1b = (const float*)d_in[9];
    const float* trans_l2w = (const float*)d_in[10];
    const float* trans_l2b = (const float*)d_in[11];
    const float* proj_w    = (const float*)d_in[12];
    const float* pret_emb  = (const float*)d_in[13];
    const float* term_l1w  = (const float*)d_in[14];
    const float* term_l1b  = (const float*)d_in[15];
    const float* term_l2w  = (const float*)d_in[16];
    const float* term_l2b  = (const float*)d_in[17];
    const float* term_ow   = (const float*)d_in[18];
    const float* term_ob   = (const float*)d_in[19];
    const int*   text      = (const int*)d_in[20];
    const int*   w2s       = (const int*)d_in[21];

    char* w = (char*)d_ws;
    const u32 MB = 1u << 20;
    const size_t CH = (size_t)C_DIM * H_DIM;   // 524288
    const size_t HH = (size_t)H_DIM * H_DIM;   // 262144

    u16*   emb16  = (u16*)(w);                          // 3 MB
    u16*   w16    = (u16*)(w + 3u * MB);                // 3 MB
    u16*   proj16 = (u16*)(w + 6u * MB);                // 1 MB
    u16*   H16    = (u16*)(w + 7u * MB);                // 3 MB
    u16*   R16    = (u16*)(w + 10u * MB);               // 3 MB
    float* TL     = (float*)(w + 13u * MB);             // 4 MB
    float* startv = (float*)(w + 17u * MB);             // 4 KB
    float* logZ   = (float*)(w + 17u * MB + 4096);      // 4 KB
    float* logrow = (float*)(w + 17u * MB + 8192);      // 4 KB
    float* Mc     = (float*)(w + 17u * MB + 12288);     // 64 KB
    float* Zpart  = (float*)(w + 18u * MB);             // 128 KB (zeroed)
    float* Ssum   = Zpart + (size_t)NSLOT * C_DIM;      // 32 floats (zeroed)
    float* rowsum = Ssum + NSLOT;                       // 1024 floats (zeroed)
    float* Lmat   = (float*)(w + 19u * MB);             // 1 MB

    u16* semb16 = emb16;
    u16* temb16 = emb16 + CH;
    u16* pemb16 = emb16 + 2 * CH;
    u16* sl1w16 = w16;
    u16* sl2w16 = w16 + HH;
    u16* tl1w16 = w16 + 2 * HH;
    u16* tl2w16 = w16 + 3 * HH;
    u16* ml1w16 = w16 + 4 * HH;
    u16* ml2w16 = w16 + 5 * HH;
    u16* Hs = H16, *Ht = H16 + CH, *Hp = H16 + 2 * CH;
    u16* Rstart16 = R16;
    u16* Rtrans16 = R16 + CH;
    u16* Rterm16  = R16 + 2 * CH;

    dim3 blk256(256);

    CvtArgs cv;
    cv.src[0] = start_emb; cv.dst[0] = semb16; cv.n[0] = (int)CH;
    cv.src[1] = state_emb; cv.dst[1] = temb16; cv.n[1] = (int)CH;
    cv.src[2] = pret_emb;  cv.dst[2] = pemb16; cv.n[2] = (int)CH;
    cv.src[3] = start_l1w; cv.dst[3] = sl1w16; cv.n[3] = (int)HH;
    cv.src[4] = start_l2w; cv.dst[4] = sl2w16; cv.n[4] = (int)HH;
    cv.src[5] = trans_l1w; cv.dst[5] = tl1w16; cv.n[5] = (int)HH;
    cv.src[6] = trans_l2w; cv.dst[6] = tl2w16; cv.n[6] = (int)HH;
    cv.src[7] = term_l1w;  cv.dst[7] = ml1w16; cv.n[7] = (int)HH;
    cv.src[8] = term_l2w;  cv.dst[8] = ml2w16; cv.n[8] = (int)HH;
    cv.src[9] = proj_w;    cv.dst[9] = proj16; cv.n[9] = (int)CH;
    cv.zero = Zpart; cv.zn = NSLOT * C_DIM + NSLOT + C_DIM;
    cvt_kern<<<dim3(128, 11), blk256, 0, stream>>>(cv);

    MlpArgs l1;
    l1.A[0] = semb16; l1.A[1] = temb16; l1.A[2] = pemb16;
    l1.W[0] = sl1w16; l1.W[1] = tl1w16; l1.W[2] = ml1w16;
    l1.bias[0] = start_l1b; l1.bias[1] = trans_l1b; l1.bias[2] = term_l1b;
    l1.resid[0] = nullptr; l1.resid[1] = nullptr; l1.resid[2] = nullptr;
    l1.out[0] = Hs; l1.out[1] = Ht; l1.out[2] = Hp;

    MlpArgs l2;
    l2.A[0] = Hs; l2.A[1] = Ht; l2.A[2] = Hp;
    l2.W[0] = sl2w16; l2.W[1] = tl2w16; l2.W[2] = ml2w16;
    l2.bias[0] = start_l2b; l2.bias[1] = trans_l2b; l2.bias[2] = term_l2b;
    l2.resid[0] = start_emb; l2.resid[1] = state_emb; l2.resid[2] = pret_emb;
    l2.out[0] = Rstart16; l2.out[1] = Rtrans16; l2.out[2] = Rterm16;

    mlp16_kern<<<dim3(16, 8, 3), blk256, 0, stream>>>(l1);
    mlp16_kern<<<dim3(16, 8, 3), blk256, 0, stream>>>(l2);

    fused_mid_kern<<<256 + V_DIM / 4 + C_DIM / 4, blk256, 0, stream>>>(
        Rtrans16, proj16, TL, rowsum,
        Rterm16, term_ow, term_ob, w2s, Zpart, Lmat,
        Rstart16, start_ow, start_ob, startv, Ssum);

    zred_kern<<<C_DIM / 256, blk256, 0, stream>>>(Zpart, rowsum, logZ, logrow);

    scanA_kern<<<B_DIM * 16, dim3(64), 0, stream>>>(TL, logrow, Lmat, logZ,
                                                    startv, Ssum, text, w2s, Mc);
    scanB_kern<<<1, 1024, 0, stream>>>(Mc, (float*)d_out);
}

// Round 4
// 212.297 us; speedup vs baseline: 1.2482x; 1.0644x over previous
//
#include <hip/hip_runtime.h>
#include <hip/hip_bf16.h>

#define C_DIM 1024
#define H_DIM 512
#define V_DIM 32000
#define B_DIM 16
#define T_DIM 256
#define SPW   8
#define NSLOT 32
#define NSEG  32   // scan segments per batch

typedef unsigned short u16;
typedef unsigned int   u32;
typedef __attribute__((ext_vector_type(8))) short bf16x8;
typedef __attribute__((ext_vector_type(4))) float f32x4;

__device__ __forceinline__ u16 f2b(float f) {
    union { float f; u32 i; } x; x.f = f;
    u32 i = x.i;
    i += 0x7fffu + ((i >> 16) & 1u);   // RNE
    return (u16)(i >> 16);
}
__device__ __forceinline__ float b2f(u16 u) {
    union { u32 i; float f; } x; x.i = ((u32)u) << 16; return x.f;
}
__device__ __forceinline__ float dot8_bf16(uint4 u, const float4 tw0, const float4 tw1) {
    return tw0.x * b2f((u16)(u.x & 0xffff)) + tw0.y * b2f((u16)(u.x >> 16))
         + tw0.z * b2f((u16)(u.y & 0xffff)) + tw0.w * b2f((u16)(u.y >> 16))
         + tw1.x * b2f((u16)(u.z & 0xffff)) + tw1.y * b2f((u16)(u.z >> 16))
         + tw1.z * b2f((u16)(u.w & 0xffff)) + tw1.w * b2f((u16)(u.w >> 16));
}

// ---------------- f32 -> bf16 convert (6 segments) + zero segment ---------------
struct CvtArgs {
    const float* src[6];
    u16*         dst[6];
    int          n[6];       // element counts (multiples of 4)
    float*       zero;       // Zpart .. Ssum .. rowsum contiguous
    int          zn;
    float*       out;        // d_out, zeroed for scanB atomics
};

__global__ __launch_bounds__(256) void cvt_kern(CvtArgs a)
{
    int seg = blockIdx.y;
    if (seg == 6) {
        for (int i = blockIdx.x * 256 + threadIdx.x; i < a.zn; i += gridDim.x * 256)
            a.zero[i] = 0.0f;
        if (blockIdx.x == 0 && threadIdx.x == 0) a.out[0] = 0.0f;
        return;
    }
    const float4* s = (const float4*)a.src[seg];
    ushort4* d = (ushort4*)a.dst[seg];
    int n4 = a.n[seg] >> 2;
    for (int i = blockIdx.x * 256 + threadIdx.x; i < n4; i += gridDim.x * 256) {
        float4 v = s[i];
        ushort4 o;
        o.x = f2b(v.x); o.y = f2b(v.y); o.z = f2b(v.z); o.w = f2b(v.w);
        d[i] = o;
    }
}

// ---------------- batched bf16 MFMA MLP layer (3 problems via z) ----------------
// out16 = relu(A@W^T + bias) (+resid_f32).  z==3 (first launch only): convert the
// layer-2 weights + proj to bf16, overlapping the latency-bound GEMM blocks.
struct MlpArgs {
    const u16*   A[3];
    const u16*   W[3];
    const float* bias[3];
    const float* resid[3];   // f32, may be null
    u16*         out[3];
    const float* csrc[4];    // z==3 cvt segments
    u16*         cdst[4];
    int          cn[4];
};

__global__ __launch_bounds__(256) void mlp16_kern(MlpArgs args)
{
    if (blockIdx.z == 3) {
        int idx = (blockIdx.y * gridDim.x + blockIdx.x) * 256 + threadIdx.x;
        int stride = gridDim.x * gridDim.y * 256;
#pragma unroll
        for (int s = 0; s < 4; s++) {
            const float4* sp = (const float4*)args.csrc[s];
            ushort4* dp = (ushort4*)args.cdst[s];
            int n4 = args.cn[s] >> 2;
            for (int t = idx; t < n4; t += stride) {
                float4 v = sp[t];
                ushort4 o;
                o.x = f2b(v.x); o.y = f2b(v.y); o.z = f2b(v.z); o.w = f2b(v.w);
                dp[t] = o;
            }
        }
        return;
    }
    const int N = H_DIM, K = H_DIM;
    int z = blockIdx.z;
    const u16* A = args.A[z];
    const u16* B = args.W[z];
    const float* bias = args.bias[z];
    const float* resid = args.resid[z];
    u16* out = args.out[z];

    __shared__ __align__(16) u16 As[2][64][40];
    __shared__ __align__(16) u16 Bs[2][64][40];
    int tid  = threadIdx.x;
    int m0 = blockIdx.x * 64, n0 = blockIdx.y * 64;
    int wave = tid >> 6, lane = tid & 63;
    int wr = wave >> 1, wc = wave & 1;
    int srow = tid >> 2, scol = (tid & 3) << 3;
    int quad = lane >> 4, l16 = lane & 15;
    f32x4 acc[2][2] = {};

    const u16* ap = A + (size_t)(m0 + srow) * K + scol;
    const u16* bp = B + (size_t)(n0 + srow) * K + scol;

    *(uint4*)&As[0][srow][scol] = *(const uint4*)ap;
    *(uint4*)&Bs[0][srow][scol] = *(const uint4*)bp;
    __syncthreads();
    int cur = 0;
#pragma unroll 1
    for (int k0 = 0; k0 + 32 < K; k0 += 32) {
        uint4 an = *(const uint4*)(ap + k0 + 32);
        uint4 bn = *(const uint4*)(bp + k0 + 32);
        bf16x8 af0 = *(const bf16x8*)&As[cur][wr * 32 + l16][quad * 8];
        bf16x8 af1 = *(const bf16x8*)&As[cur][wr * 32 + 16 + l16][quad * 8];
        bf16x8 bf0 = *(const bf16x8*)&Bs[cur][wc * 32 + l16][quad * 8];
        bf16x8 bf1 = *(const bf16x8*)&Bs[cur][wc * 32 + 16 + l16][quad * 8];
        acc[0][0] = __builtin_amdgcn_mfma_f32_16x16x32_bf16(af0, bf0, acc[0][0], 0, 0, 0);
        acc[0][1] = __builtin_amdgcn_mfma_f32_16x16x32_bf16(af0, bf1, acc[0][1], 0, 0, 0);
        acc[1][0] = __builtin_amdgcn_mfma_f32_16x16x32_bf16(af1, bf0, acc[1][0], 0, 0, 0);
        acc[1][1] = __builtin_amdgcn_mfma_f32_16x16x32_bf16(af1, bf1, acc[1][1], 0, 0, 0);
        *(uint4*)&As[cur ^ 1][srow][scol] = an;
        *(uint4*)&Bs[cur ^ 1][srow][scol] = bn;
        __syncthreads();
        cur ^= 1;
    }
    {
        bf16x8 af0 = *(const bf16x8*)&As[cur][wr * 32 + l16][quad * 8];
        bf16x8 af1 = *(const bf16x8*)&As[cur][wr * 32 + 16 + l16][quad * 8];
        bf16x8 bf0 = *(const bf16x8*)&Bs[cur][wc * 32 + l16][quad * 8];
        bf16x8 bf1 = *(const bf16x8*)&Bs[cur][wc * 32 + 16 + l16][quad * 8];
        acc[0][0] = __builtin_amdgcn_mfma_f32_16x16x32_bf16(af0, bf0, acc[0][0], 0, 0, 0);
        acc[0][1] = __builtin_amdgcn_mfma_f32_16x16x32_bf16(af0, bf1, acc[0][1], 0, 0, 0);
        acc[1][0] = __builtin_amdgcn_mfma_f32_16x16x32_bf16(af1, bf0, acc[1][0], 0, 0, 0);
        acc[1][1] = __builtin_amdgcn_mfma_f32_16x16x32_bf16(af1, bf1, acc[1][1], 0, 0, 0);
    }
#pragma unroll
    for (int sm = 0; sm < 2; sm++)
#pragma unroll
        for (int sn = 0; sn < 2; sn++) {
            int n = n0 + wc * 32 + sn * 16 + l16;
            float bv = bias[n];
#pragma unroll
            for (int reg = 0; reg < 4; reg++) {
                int m = m0 + wr * 32 + sm * 16 + quad * 4 + reg;
                float v = fmaxf(acc[sm][sn][reg] + bv, 0.0f);
                if (resid) v += resid[(size_t)m * N + n];
                out[(size_t)m * N + n] = f2b(v);
            }
        }
}

// ---------------- fused: transGEMM(256) + zsum(4000, 2 words/wave) + start ------
__global__ __launch_bounds__(256) void fused_mid_kern(
    const u16* __restrict__ Rtrans16, const u16* __restrict__ proj16,
    float* __restrict__ TL, float* __restrict__ rowsum,
    const u16* __restrict__ Rterm16, const float* __restrict__ tow,
    const float* __restrict__ tob, const int* __restrict__ w2s,
    float* __restrict__ Zpart, float* __restrict__ Lmat,
    const u16* __restrict__ Rstart16, const float* __restrict__ sow,
    const float* __restrict__ sob, float* __restrict__ startv,
    float* __restrict__ Ssum)
{
    __shared__ __align__(16) u16 As[2][64][40];
    __shared__ __align__(16) u16 Bs[2][64][40];
    int bx = blockIdx.x;
    int tid = threadIdx.x;
    int wid = tid >> 6, lane = tid & 63;

    if (bx < 256) {
        // ---- trans GEMM: TL = Rtrans16 @ proj16^T, rowsum += sum exp ----
        const int K = H_DIM;
        int m0 = (bx & 15) * 64, n0 = (bx >> 4) * 64;
        int wr = wid >> 1, wc = wid & 1;
        int srow = tid >> 2, scol = (tid & 3) << 3;
        int quad = lane >> 4, l16 = lane & 15;
        f32x4 acc[2][2] = {};

        const u16* ap = Rtrans16 + (size_t)(m0 + srow) * K + scol;
        const u16* bp = proj16 + (size_t)(n0 + srow) * K + scol;

        *(uint4*)&As[0][srow][scol] = *(const uint4*)ap;
        *(uint4*)&Bs[0][srow][scol] = *(const uint4*)bp;
        __syncthreads();
        int cur = 0;
#pragma unroll 1
        for (int k0 = 0; k0 + 32 < K; k0 += 32) {
            uint4 an = *(const uint4*)(ap + k0 + 32);
            uint4 bn = *(const uint4*)(bp + k0 + 32);
            bf16x8 af0 = *(const bf16x8*)&As[cur][wr * 32 + l16][quad * 8];
            bf16x8 af1 = *(const bf16x8*)&As[cur][wr * 32 + 16 + l16][quad * 8];
            bf16x8 bf0 = *(const bf16x8*)&Bs[cur][wc * 32 + l16][quad * 8];
            bf16x8 bf1 = *(const bf16x8*)&Bs[cur][wc * 32 + 16 + l16][quad * 8];
            acc[0][0] = __builtin_amdgcn_mfma_f32_16x16x32_bf16(af0, bf0, acc[0][0], 0, 0, 0);
            acc[0][1] = __builtin_amdgcn_mfma_f32_16x16x32_bf16(af0, bf1, acc[0][1], 0, 0, 0);
            acc[1][0] = __builtin_amdgcn_mfma_f32_16x16x32_bf16(af1, bf0, acc[1][0], 0, 0, 0);
            acc[1][1] = __builtin_amdgcn_mfma_f32_16x16x32_bf16(af1, bf1, acc[1][1], 0, 0, 0);
            *(uint4*)&As[cur ^ 1][srow][scol] = an;
            *(uint4*)&Bs[cur ^ 1][srow][scol] = bn;
            __syncthreads();
            cur ^= 1;
        }
        {
            bf16x8 af0 = *(const bf16x8*)&As[cur][wr * 32 + l16][quad * 8];
            bf16x8 af1 = *(const bf16x8*)&As[cur][wr * 32 + 16 + l16][quad * 8];
            bf16x8 bf0 = *(const bf16x8*)&Bs[cur][wc * 32 + l16][quad * 8];
            bf16x8 bf1 = *(const bf16x8*)&Bs[cur][wc * 32 + 16 + l16][quad * 8];
            acc[0][0] = __builtin_amdgcn_mfma_f32_16x16x32_bf16(af0, bf0, acc[0][0], 0, 0, 0);
            acc[0][1] = __builtin_amdgcn_mfma_f32_16x16x32_bf16(af0, bf1, acc[0][1], 0, 0, 0);
            acc[1][0] = __builtin_amdgcn_mfma_f32_16x16x32_bf16(af1, bf0, acc[1][0], 0, 0, 0);
            acc[1][1] = __builtin_amdgcn_mfma_f32_16x16x32_bf16(af1, bf1, acc[1][1], 0, 0, 0);
        }
#pragma unroll
        for (int sm = 0; sm < 2; sm++)
#pragma unroll
            for (int reg = 0; reg < 4; reg++) {
                int m = m0 + wr * 32 + sm * 16 + quad * 4 + reg;
                float e = 0.0f;
#pragma unroll
                for (int sn = 0; sn < 2; sn++) {
                    int n = n0 + wc * 32 + sn * 16 + l16;
                    float v = acc[sm][sn][reg];
                    TL[(size_t)m * C_DIM + n] = v;
                    e += __expf(v);
                }
                e += __shfl_xor(e, 1, 64);
                e += __shfl_xor(e, 2, 64);
                e += __shfl_xor(e, 4, 64);
                e += __shfl_xor(e, 8, 64);
                if (l16 == 0) atomicAdd(rowsum + m, e);
            }
        return;
    }

    if (bx < 256 + V_DIM / 8) {
        // ---- emission logits + denominator: 2 words per wave for ILP ----
        int qbid = bx - 256;                  // 0..3999
        int slotid = qbid & (NSLOT - 1);
#pragma unroll
        for (int h = 0; h < 2; h++) {
            int v = (qbid * 4 + wid) * 2 + h;
            const float4* twp = (const float4*)(tow + (size_t)v * H_DIM);
            float4 tw0 = twp[lane * 2], tw1 = twp[lane * 2 + 1];
            float ob = tob[v];
            int cs[SPW];
#pragma unroll
            for (int s = 0; s < SPW; s++) cs[s] = w2s[v * SPW + s];
            uint4 rv[SPW];
#pragma unroll
            for (int s = 0; s < SPW; s++)
                rv[s] = ((const uint4*)(Rterm16 + (size_t)cs[s] * H_DIM))[lane];
            float d[SPW];
#pragma unroll
            for (int s = 0; s < SPW; s++) {
                d[s] = dot8_bf16(rv[s], tw0, tw1);
                d[s] += __shfl_xor(d[s], 1, 64);
                d[s] += __shfl_xor(d[s], 2, 64);
                d[s] += __shfl_xor(d[s], 4, 64);
            }
            float x = d[0];
            int myc = cs[0];
#pragma unroll
            for (int s = 1; s < SPW; s++) {
                if ((lane & 7) == s) { x = d[s]; myc = cs[s]; }
            }
            x += __shfl_xor(x, 8, 64);
            x += __shfl_xor(x, 16, 64);
            x += __shfl_xor(x, 32, 64);
            u32 dupmask = 0;
#pragma unroll
            for (int s = 1; s < SPW; s++) {
                bool dp = false;
#pragma unroll
                for (int s2 = 0; s2 < s; s2++) dp = dp || (cs[s2] == cs[s]);
                if (dp) dupmask |= (1u << s);
            }
            if (lane < 8) {
                Lmat[(size_t)v * SPW + lane] = x + ob;
                if (!((dupmask >> lane) & 1u))
                    atomicAdd(Zpart + (size_t)myc * NSLOT + slotid, __expf(x + ob));
            }
        }
        return;
    }

    // ---- start logits ----
    int sbid = bx - (256 + V_DIM / 8);
    int c = sbid * 4 + wid;
    uint4 rv = ((const uint4*)(Rstart16 + (size_t)c * H_DIM))[lane];
    const float4* wp = (const float4*)(sow);
    float4 w0 = wp[lane * 2], w1 = wp[lane * 2 + 1];
    float d = dot8_bf16(rv, w0, w1);
    for (int off = 1; off < 64; off <<= 1) d += __shfl_xor(d, off, 64);
    if (lane == 0) {
        d += sob[0];
        startv[c] = d;
        atomicAdd(Ssum + (sbid & (NSLOT - 1)), __expf(d));
    }
}

// ---------------- log-semiring 8x8 matrix combine (lane = j*8+i) ----------------
__device__ __forceinline__ float lsm_combine(float accv, float mv, int i, int j)
{
    float x[8];
#pragma unroll
    for (int k = 0; k < 8; k++) {
        float a = __shfl(accv, k * 8 + i, 64);   // acc[i][k]
        float b = __shfl(mv,  j * 8 + k, 64);    // m[k][j]
        x[k] = a + b;
    }
    float mx = fmaxf(fmaxf(fmaxf(x[0], x[1]), fmaxf(x[2], x[3])),
                     fmaxf(fmaxf(x[4], x[5]), fmaxf(x[6], x[7])));
    float s = 0.0f;
#pragma unroll
    for (int k = 0; k < 8; k++) s += __expf(x[k] - mx);
    return mx + __logf(s);
}

// ---------------- fused potential + scan phase A (NSEG segs/batch) --------------
// Inlines the Zpart/rowsum reductions (logZ/logrow tables in LDS) — no zred pass.
__global__ __launch_bounds__(64) void scanA_kern(
    const float* __restrict__ TL, const float* __restrict__ rowsum,
    const float* __restrict__ Lmat, const float* __restrict__ Zpart,
    const float* __restrict__ startv, const float* __restrict__ Ssum,
    const int* __restrict__ text, const int* __restrict__ w2s,
    float* __restrict__ Mc)
{
    __shared__ float sLZ[C_DIM];
    __shared__ float sLR[C_DIM];
    int lane = threadIdx.x;
    for (int c = lane; c < C_DIM; c += 64) {
        const float4* zp = (const float4*)(Zpart + (size_t)c * NSLOT);
        float4 z0 = zp[0], z1 = zp[1], z2 = zp[2], z3 = zp[3];
        float4 z4 = zp[4], z5 = zp[5], z6 = zp[6], z7 = zp[7];
        float z = ((z0.x + z0.y + z0.z + z0.w) + (z1.x + z1.y + z1.z + z1.w))
                + ((z2.x + z2.y + z2.z + z2.w) + (z3.x + z3.y + z3.z + z3.w))
                + ((z4.x + z4.y + z4.z + z4.w) + (z5.x + z5.y + z5.z + z5.w))
                + ((z6.x + z6.y + z6.z + z6.w) + (z7.x + z7.y + z7.z + z7.w));
        sLZ[c] = __logf(z);
        sLR[c] = __logf(rowsum[c]);
    }
    __syncthreads();

    int g = blockIdx.x;                  // 0 .. B*NSEG-1
    int b = g >> 5, c = g & (NSEG - 1);
    int t0 = c * ((T_DIM) / NSEG);       // 8 steps per segment
    int cnt = min(T_DIM / NSEG, (T_DIM - 1) - t0);
    int i = lane & 7, j = lane >> 3;

    const int* txt = text + b * T_DIM;

    float logS = 0.0f;
    if (t0 == 0) {
        float ss = 0.0f;
#pragma unroll
        for (int k = 0; k < NSLOT; k++) ss += Ssum[k];
        logS = __logf(ss);
    }

    auto potval = [&](int t) -> float {
        int vt  = txt[t];
        int vt1 = txt[t + 1];
        int ci = w2s[vt * SPW + i];
        int cj = w2s[vt1 * SPW + j];
        float p = TL[(size_t)ci * C_DIM + cj] - sLR[ci]
                + Lmat[(size_t)vt1 * SPW + j] - sLZ[cj];
        if (t == 0)
            p += startv[ci] - logS + Lmat[(size_t)vt * SPW + i] - sLZ[ci];
        return p;
    };

    float acc = potval(t0);
    if (cnt > 1) {
        float nv = potval(t0 + 1);
        for (int t = t0 + 1; t < t0 + cnt; t++) {
            float nv2 = (t + 1 < t0 + cnt) ? potval(t + 1) : 0.0f;
            acc = lsm_combine(acc, nv, i, j);
            nv = nv2;
        }
    }
    Mc[(size_t)g * 64 + lane] = acc;
}

// ---------------- scan phase B: block per batch, 8-wave tree, atomic out --------
__global__ __launch_bounds__(512) void scanB_kern(const float* __restrict__ Mc,
                                                  float* __restrict__ out)
{
    __shared__ float Lb[8][64];
    int b = blockIdx.x;
    int w = threadIdx.x >> 6, lane = threadIdx.x & 63;
    int i = lane & 7, j = lane >> 3;
    const float* base = Mc + (size_t)b * NSEG * 64;

    // level 0: each wave folds 4 consecutive segment matrices
    float m0 = base[(size_t)(4 * w + 0) * 64 + lane];
    float m1 = base[(size_t)(4 * w + 1) * 64 + lane];
    float m2 = base[(size_t)(4 * w + 2) * 64 + lane];
    float m3 = base[(size_t)(4 * w + 3) * 64 + lane];
    float r01 = lsm_combine(m0, m1, i, j);
    float r23 = lsm_combine(m2, m3, i, j);
    float r = lsm_combine(r01, r23, i, j);
    Lb[w][lane] = r;
    __syncthreads();
    // level 1: 8 -> 4
    float a, m;
    if (w < 4) { a = Lb[2 * w][lane]; m = Lb[2 * w + 1][lane]; r = lsm_combine(a, m, i, j); }
    __syncthreads();
    if (w < 4) Lb[w][lane] = r;
    __syncthreads();
    // level 2: 4 -> 2
    if (w < 2) { a = Lb[2 * w][lane]; m = Lb[2 * w + 1][lane]; r = lsm_combine(a, m, i, j); }
    __syncthreads();
    if (w < 2) Lb[w][lane] = r;
    __syncthreads();
    // level 3: 2 -> 1, then logsumexp over all 64 entries
    if (w == 0) {
        a = Lb[0][lane]; m = Lb[1][lane];
        r = lsm_combine(a, m, i, j);
        float mx = r;
        for (int o = 1; o < 64; o <<= 1) mx = fmaxf(mx, __shfl_xor(mx, o, 64));
        float e = __expf(r - mx);
        for (int o = 1; o < 64; o <<= 1) e += __shfl_xor(e, o, 64);
        if (lane == 0) atomicAdd(out, mx + __logf(e));
    }
}

extern "C" void kernel_launch(void* const* d_in, const int* in_sizes, int n_in,
                              void* d_out, int out_size, void* d_ws, size_t ws_size,
                              hipStream_t stream)
{
    const float* start_emb = (const float*)d_in[0];
    const float* start_l1w = (const float*)d_in[1];
    const float* start_l1b = (const float*)d_in[2];
    const float* start_l2w = (const float*)d_in[3];
    const float* start_l2b = (const float*)d_in[4];
    const float* start_ow  = (const float*)d_in[5];
    const float* start_ob  = (const float*)d_in[6];
    const float* state_emb = (const float*)d_in[7];
    const float* trans_l1w = (const float*)d_in[8];
    const float* trans_l1b = (const float*)d_in[9];
    const float* trans_l2w = (const float*)d_in[10];
    const float* trans_l2b = (const float*)d_in[11];
    const float* proj_w    = (const float*)d_in[12];
    const float* pret_emb  = (const float*)d_in[13];
    const float* term_l1w  = (const float*)d_in[14];
    const float* term_l1b  = (const float*)d_in[15];
    const float* term_l2w  = (const float*)d_in[16];
    const float* term_l2b  = (const float*)d_in[17];
    const float* term_ow   = (const float*)d_in[18];
    const float* term_ob   = (const float*)d_in[19];
    const int*   text      = (const int*)d_in[20];
    const int*   w2s       = (const int*)d_in[21];

    char* w = (char*)d_ws;
    const u32 MB = 1u << 20;
    const size_t CH = (size_t)C_DIM * H_DIM;   // 524288
    const size_t HH = (size_t)H_DIM * H_DIM;   // 262144

    u16*   emb16  = (u16*)(w);                          // 3 MB
    u16*   w16    = (u16*)(w + 3u * MB);                // 3 MB
    u16*   proj16 = (u16*)(w + 6u * MB);                // 1 MB
    u16*   H16    = (u16*)(w + 7u * MB);                // 3 MB
    u16*   R16    = (u16*)(w + 10u * MB);               // 3 MB
    float* TL     = (float*)(w + 13u * MB);             // 4 MB
    float* startv = (float*)(w + 17u * MB);             // 4 KB
    float* Mc     = (float*)(w + 17u * MB + 4096);      // 128 KB
    float* Zpart  = (float*)(w + 18u * MB);             // [C][NSLOT] 128 KB (zeroed)
    float* Ssum   = Zpart + (size_t)C_DIM * NSLOT;      // 32 floats (zeroed)
    float* rowsum = Ssum + NSLOT;                       // 1024 floats (zeroed)
    float* Lmat   = (float*)(w + 19u * MB);             // 1 MB

    u16* semb16 = emb16;
    u16* temb16 = emb16 + CH;
    u16* pemb16 = emb16 + 2 * CH;
    u16* sl1w16 = w16;
    u16* sl2w16 = w16 + HH;
    u16* tl1w16 = w16 + 2 * HH;
    u16* tl2w16 = w16 + 3 * HH;
    u16* ml1w16 = w16 + 4 * HH;
    u16* ml2w16 = w16 + 5 * HH;
    u16* Hs = H16, *Ht = H16 + CH, *Hp = H16 + 2 * CH;
    u16* Rstart16 = R16;
    u16* Rtrans16 = R16 + CH;
    u16* Rterm16  = R16 + 2 * CH;

    dim3 blk256(256);

    CvtArgs cv;
    cv.src[0] = start_emb; cv.dst[0] = semb16; cv.n[0] = (int)CH;
    cv.src[1] = state_emb; cv.dst[1] = temb16; cv.n[1] = (int)CH;
    cv.src[2] = pret_emb;  cv.dst[2] = pemb16; cv.n[2] = (int)CH;
    cv.src[3] = start_l1w; cv.dst[3] = sl1w16; cv.n[3] = (int)HH;
    cv.src[4] = trans_l1w; cv.dst[4] = tl1w16; cv.n[4] = (int)HH;
    cv.src[5] = term_l1w;  cv.dst[5] = ml1w16; cv.n[5] = (int)HH;
    cv.zero = Zpart; cv.zn = C_DIM * NSLOT + NSLOT + C_DIM;
    cv.out = (float*)d_out;
    cvt_kern<<<dim3(64, 7), blk256, 0, stream>>>(cv);

    MlpArgs l1;
    l1.A[0] = semb16; l1.A[1] = temb16; l1.A[2] = pemb16;
    l1.W[0] = sl1w16; l1.W[1] = tl1w16; l1.W[2] = ml1w16;
    l1.bias[0] = start_l1b; l1.bias[1] = trans_l1b; l1.bias[2] = term_l1b;
    l1.resid[0] = nullptr; l1.resid[1] = nullptr; l1.resid[2] = nullptr;
    l1.out[0] = Hs; l1.out[1] = Ht; l1.out[2] = Hp;
    l1.csrc[0] = start_l2w; l1.cdst[0] = sl2w16; l1.cn[0] = (int)HH;
    l1.csrc[1] = trans_l2w; l1.cdst[1] = tl2w16; l1.cn[1] = (int)HH;
    l1.csrc[2] = term_l2w;  l1.cdst[2] = ml2w16; l1.cn[2] = (int)HH;
    l1.csrc[3] = proj_w;    l1.cdst[3] = proj16; l1.cn[3] = (int)CH;

    MlpArgs l2;
    l2.A[0] = Hs; l2.A[1] = Ht; l2.A[2] = Hp;
    l2.W[0] = sl2w16; l2.W[1] = tl2w16; l2.W[2] = ml2w16;
    l2.bias[0] = start_l2b; l2.bias[1] = trans_l2b; l2.bias[2] = term_l2b;
    l2.resid[0] = start_emb; l2.resid[1] = state_emb; l2.resid[2] = pret_emb;
    l2.out[0] = Rstart16; l2.out[1] = Rtrans16; l2.out[2] = Rterm16;
    l2.csrc[0] = nullptr; l2.cdst[0] = nullptr; l2.cn[0] = 0;
    l2.csrc[1] = nullptr; l2.cdst[1] = nullptr; l2.cn[1] = 0;
    l2.csrc[2] = nullptr; l2.cdst[2] = nullptr; l2.cn[2] = 0;
    l2.csrc[3] = nullptr; l2.cdst[3] = nullptr; l2.cn[3] = 0;

    mlp16_kern<<<dim3(16, 8, 4), blk256, 0, stream>>>(l1);
    mlp16_kern<<<dim3(16, 8, 3), blk256, 0, stream>>>(l2);

    fused_mid_kern<<<256 + V_DIM / 8 + C_DIM / 4, blk256, 0, stream>>>(
        Rtrans16, proj16, TL, rowsum,
        Rterm16, term_ow, term_ob, w2s, Zpart, Lmat,
        Rstart16, start_ow, start_ob, startv, Ssum);

    scanA_kern<<<B_DIM * NSEG, dim3(64), 0, stream>>>(TL, rowsum, Lmat, Zpart,
                                                      startv, Ssum, text, w2s, Mc);
    scanB_kern<<<B_DIM, dim3(512), 0, stream>>>(Mc, (float*)d_out);
}